// Round 2
// baseline (1610.322 us; speedup 1.0000x reference)
//
#include <hip/hip_runtime.h>

// Sizes fixed by the problem
#define NR 120000   // occupied voxels
#define CI 32
#define CO 64
#define KK 27
#define BM 128      // rows per block

// ---------------------------------------------------------------------------
// K1: sparse conv1 (32->64, 27 offsets) + fused classifier/mask + compaction.
// Block: 256 threads = 4 waves. Thread tile: 4 channels x 8 rows.
//   dq = t & 15  -> channels 4*dq .. 4*dq+3
//   rq = t >> 4  -> rows rp*16 + rq, rp = 0..7
// Writes: x1 (all rows), out = 2*x1 (all rows; strong rows overwritten by K2),
//         mk[i] = strong?, sids[] compacted strong ids, cnt = #strong.
// ---------------------------------------------------------------------------
__global__ __launch_bounds__(256, 2)
void k_conv1(const float* __restrict__ xF, const float* __restrict__ gum,
             const int* __restrict__ nbr, const float* __restrict__ Wch,
             const float* __restrict__ bch, const float* __restrict__ Wcls,
             const float* __restrict__ bcls,
             float* __restrict__ x1, unsigned* __restrict__ mk,
             int* __restrict__ sids, int* __restrict__ cnt,
             float* __restrict__ outp)
{
    __shared__ int   nbr_s[BM * KK];     // 13824 B
    __shared__ float gs[BM][CI + 4];     // +4 pad: row stride 36 = 4 (mod 32) banks
    __shared__ float Ws[CI][CO];         // 8 KB
    __shared__ int   sl[BM];
    __shared__ int   scnt, sbase;

    const int t  = threadIdx.x;
    const int dq = t & 15;
    const int rq = t >> 4;
    const int row0 = blockIdx.x * BM;

    if (t == 0) scnt = 0;

    // stage neighbor indices for the block's 128 rows
    for (int idx = t; idx < BM * KK; idx += 256) {
        int r = idx / KK;
        int i = row0 + r;
        nbr_s[idx] = (i < NR) ? nbr[i * KK + (idx - r * KK)] : NR;
    }

    const float4 bq = reinterpret_cast<const float4*>(bch)[dq];
    float4 acc[8];
#pragma unroll
    for (int rp = 0; rp < 8; ++rp) acc[rp] = bq;

    // classifier weights for this thread's channel quad
    float wc[4][2];
#pragma unroll
    for (int c = 0; c < 4; ++c) {
        wc[c][0] = Wcls[(dq * 4 + c) * 2 + 0];
        wc[c][1] = Wcls[(dq * 4 + c) * 2 + 1];
    }
    const float b0 = bcls[0], b1 = bcls[1];

    __syncthreads();

#pragma unroll 1
    for (int k = 0; k < KK; ++k) {
        // stage W[k] : 32x64 floats = 512 float4
        {
            const float4* Wk = reinterpret_cast<const float4*>(Wch + (size_t)k * CI * CO);
            float4* Wv = reinterpret_cast<float4*>(&Ws[0][0]);
            Wv[t]       = Wk[t];
            Wv[t + 256] = Wk[t + 256];
        }
        // stage gathered rows: 128 rows x 8 quads = 1024 slots
#pragma unroll
        for (int p = 0; p < 4; ++p) {
            int slot = p * 256 + t;
            int r = slot >> 3, q = slot & 7;
            int j = nbr_s[r * KK + k];
            float4 v = make_float4(0.f, 0.f, 0.f, 0.f);
            if (j < NR) v = reinterpret_cast<const float4*>(xF + (size_t)j * CI)[q];
            *reinterpret_cast<float4*>(&gs[r][q * 4]) = v;
        }
        __syncthreads();

#pragma unroll
        for (int cq = 0; cq < CI / 4; ++cq) {
            float4 w0 = *reinterpret_cast<const float4*>(&Ws[cq * 4 + 0][dq * 4]);
            float4 w1 = *reinterpret_cast<const float4*>(&Ws[cq * 4 + 1][dq * 4]);
            float4 w2 = *reinterpret_cast<const float4*>(&Ws[cq * 4 + 2][dq * 4]);
            float4 w3 = *reinterpret_cast<const float4*>(&Ws[cq * 4 + 3][dq * 4]);
#pragma unroll
            for (int rp = 0; rp < 8; ++rp) {
                float4 g = *reinterpret_cast<const float4*>(&gs[rp * 16 + rq][cq * 4]);
                acc[rp].x += g.x * w0.x + g.y * w1.x + g.z * w2.x + g.w * w3.x;
                acc[rp].y += g.x * w0.y + g.y * w1.y + g.z * w2.y + g.w * w3.y;
                acc[rp].z += g.x * w0.z + g.y * w1.z + g.z * w2.z + g.w * w3.z;
                acc[rp].w += g.x * w0.w + g.y * w1.w + g.z * w2.w + g.w * w3.w;
            }
        }
        __syncthreads();
    }

    // epilogue: write x1, out=2*x1, classifier -> mask + block compaction
#pragma unroll
    for (int rp = 0; rp < 8; ++rp) {
        float4 a = acc[rp];
        float p0 = a.x * wc[0][0] + a.y * wc[1][0] + a.z * wc[2][0] + a.w * wc[3][0];
        float p1 = a.x * wc[0][1] + a.y * wc[1][1] + a.z * wc[2][1] + a.w * wc[3][1];
#pragma unroll
        for (int off = 1; off < 16; off <<= 1) {
            p0 += __shfl_xor(p0, off, 64);
            p1 += __shfl_xor(p1, off, 64);
        }
        int i = row0 + rp * 16 + rq;
        if (i < NR) {
            reinterpret_cast<float4*>(x1 + (size_t)i * CO)[dq] = a;
            float4 o = make_float4(2.f * a.x, 2.f * a.y, 2.f * a.z, 2.f * a.w);
            reinterpret_cast<float4*>(outp + (size_t)i * CO)[dq] = o;
            if (dq == 0) {
                float z0 = p0 + b0 + gum[2 * i + 0];
                float z1 = p1 + b1 + gum[2 * i + 1];
                unsigned m = (z0 >= z1) ? 1u : 0u;   // argmax tie -> index 0 -> strong
                mk[i] = m;
                if (m) { int pos = atomicAdd(&scnt, 1); sl[pos] = i; }
            }
        }
    }
    __syncthreads();
    if (t == 0) sbase = atomicAdd(cnt, scnt);
    __syncthreads();
    if (t < scnt) sids[sbase + t] = sl[t];
}

// ---------------------------------------------------------------------------
// K2: sparse conv2 (64->64) over compacted strong rows; gathers mask-predicated
// x1 rows; writes out[sid] = acc + b_dw + x1[sid].
// ---------------------------------------------------------------------------
__global__ __launch_bounds__(256, 2)
void k_conv2(const float* __restrict__ x1, const int* __restrict__ nbr,
             const float* __restrict__ Wdw, const float* __restrict__ bdw,
             const unsigned* __restrict__ mk, const int* __restrict__ sids,
             const int* __restrict__ cnt, float* __restrict__ outp)
{
    const int nstrong = *cnt;
    const int row0 = blockIdx.x * BM;
    if (row0 >= nstrong) return;

    __shared__ int   nbr_s[BM * KK];     // 13824 B
    __shared__ float gs[BM][CO + 4];     // 34816 B, stride 68 = 4 (mod 32)
    __shared__ float Ws[CO][CO];         // 16 KB

    const int t  = threadIdx.x;
    const int dq = t & 15;
    const int rq = t >> 4;

    for (int idx = t; idx < BM * KK; idx += 256) {
        int r  = idx / KK;
        int rr = row0 + r;
        int sid = (rr < nstrong) ? sids[rr] : -1;
        nbr_s[idx] = (sid >= 0) ? nbr[sid * KK + (idx - r * KK)] : NR;
    }

    float4 acc[8];
#pragma unroll
    for (int rp = 0; rp < 8; ++rp) acc[rp] = make_float4(0.f, 0.f, 0.f, 0.f);

    __syncthreads();

#pragma unroll 1
    for (int k = 0; k < KK; ++k) {
        // stage W[k] : 64x64 floats = 1024 float4
        {
            const float4* Wk = reinterpret_cast<const float4*>(Wdw + (size_t)k * CO * CO);
            float4* Wv = reinterpret_cast<float4*>(&Ws[0][0]);
            Wv[t]       = Wk[t];
            Wv[t + 256] = Wk[t + 256];
            Wv[t + 512] = Wk[t + 512];
            Wv[t + 768] = Wk[t + 768];
        }
        // stage gathered x1 rows (mask-predicated): 128 rows x 16 quads
#pragma unroll
        for (int p = 0; p < 8; ++p) {
            int slot = p * 256 + t;
            int r = slot >> 4, q = slot & 15;
            int j = nbr_s[r * KK + k];
            float4 v = make_float4(0.f, 0.f, 0.f, 0.f);
            if (j < NR) {
                if (mk[j]) v = reinterpret_cast<const float4*>(x1 + (size_t)j * CO)[q];
            }
            *reinterpret_cast<float4*>(&gs[r][q * 4]) = v;
        }
        __syncthreads();

#pragma unroll
        for (int cq = 0; cq < CO / 4; ++cq) {
            float4 w0 = *reinterpret_cast<const float4*>(&Ws[cq * 4 + 0][dq * 4]);
            float4 w1 = *reinterpret_cast<const float4*>(&Ws[cq * 4 + 1][dq * 4]);
            float4 w2 = *reinterpret_cast<const float4*>(&Ws[cq * 4 + 2][dq * 4]);
            float4 w3 = *reinterpret_cast<const float4*>(&Ws[cq * 4 + 3][dq * 4]);
#pragma unroll
            for (int rp = 0; rp < 8; ++rp) {
                float4 g = *reinterpret_cast<const float4*>(&gs[rp * 16 + rq][cq * 4]);
                acc[rp].x += g.x * w0.x + g.y * w1.x + g.z * w2.x + g.w * w3.x;
                acc[rp].y += g.x * w0.y + g.y * w1.y + g.z * w2.y + g.w * w3.y;
                acc[rp].z += g.x * w0.z + g.y * w1.z + g.z * w2.z + g.w * w3.z;
                acc[rp].w += g.x * w0.w + g.y * w1.w + g.z * w2.w + g.w * w3.w;
            }
        }
        __syncthreads();
    }

    const float4 bq = reinterpret_cast<const float4*>(bdw)[dq];
#pragma unroll
    for (int rp = 0; rp < 8; ++rp) {
        int rr = row0 + rp * 16 + rq;
        if (rr < nstrong) {
            int sid = sids[rr];
            float4 xv = reinterpret_cast<const float4*>(x1 + (size_t)sid * CO)[dq];
            float4 a  = acc[rp];
            float4 o  = make_float4(a.x + bq.x + xv.x, a.y + bq.y + xv.y,
                                    a.z + bq.z + xv.z, a.w + bq.w + xv.w);
            reinterpret_cast<float4*>(outp + (size_t)sid * CO)[dq] = o;
        }
    }
}

// ---------------------------------------------------------------------------
extern "C" void kernel_launch(void* const* d_in, const int* in_sizes, int n_in,
                              void* d_out, int out_size, void* d_ws, size_t ws_size,
                              hipStream_t stream)
{
    const float* xF   = (const float*)d_in[0];
    const float* gum  = (const float*)d_in[1];
    const int*   nbr  = (const int*)d_in[2];
    const float* Wch  = (const float*)d_in[3];
    const float* bch  = (const float*)d_in[4];
    const float* Wcls = (const float*)d_in[5];
    const float* bcls = (const float*)d_in[6];
    const float* Wdw  = (const float*)d_in[7];
    const float* bdw  = (const float*)d_in[8];
    // d_in[9] = th (unused by the forward computation)

    float* outp = (float*)d_out;
    char*  ws   = (char*)d_ws;

    // ws layout (all 16B aligned): x1 [N*64 f32] | mk [N u32] | sids [N i32] | cnt [i32]
    float*    x1   = (float*)(ws);
    unsigned* mk   = (unsigned*)(ws + (size_t)NR * CO * 4);
    int*      sids = (int*)(ws + (size_t)NR * CO * 4 + (size_t)NR * 4);
    int*      cnt  = (int*)(ws + (size_t)NR * CO * 4 + (size_t)NR * 8);

    hipMemsetAsync(cnt, 0, sizeof(int), stream);

    const int nb = (NR + BM - 1) / BM;  // 938
    hipLaunchKernelGGL(k_conv1, dim3(nb), dim3(256), 0, stream,
                       xF, gum, nbr, Wch, bch, Wcls, bcls, x1, mk, sids, cnt, outp);
    hipLaunchKernelGGL(k_conv2, dim3(nb), dim3(256), 0, stream,
                       x1, nbr, Wdw, bdw, mk, sids, cnt, outp);
}